// Round 2
// baseline (262.529 us; speedup 1.0000x reference)
//
#include <hip/hip_runtime.h>
#include <hip/hip_bf16.h>

// Causal attention B=2,H=12,S=2048,D=64 fp32 in/out.
// R2 design: pre-pass converts Q (scaled by log2e/8 -> base-2 softmax), K to
// bf16 and V to bf16 TRANSPOSED [bh][d][s] in d_ws. Main kernel then reads all
// MFMA fragments directly from global (16B/lane coalesced) -> NO K/V LDS, NO
// __syncthreads in the k-loop. Only wave-private P C->A layout round trip in
// LDS (lgkmcnt-ordered within the wave). Falls back to the R1 staged kernel
// if ws_size is too small.

#define SEQ 2048
#define DH 64
#define NHEADS 24          // B*H
#define BM 64
#define BN 64
#define LDK 72
#define ELEMS_PER_TENSOR (NHEADS * SEQ * DH)          // 3145728
#define WS_NEEDED ((size_t)3 * ELEMS_PER_TENSOR * 2)  // 18874368 B

typedef float f32x4 __attribute__((ext_vector_type(4)));
typedef __bf16 bf16x8 __attribute__((ext_vector_type(8)));

#if __has_builtin(__builtin_amdgcn_exp2f)
#define EXP2F(x) __builtin_amdgcn_exp2f(x)
#else
#define EXP2F(x) exp2f(x)
#endif

// log2(e)/8: folds both the 1/sqrt(64) scale and the nat->base-2 change into Q
#define QSCALE 0.1803368801111204f

// ---------------- pre-pass: convert Q (scaled) and K to bf16 ----------------
__global__ __launch_bounds__(256)
void cvt_qk_kernel(const float* __restrict__ q, const float* __restrict__ k,
                   __bf16* __restrict__ qs, __bf16* __restrict__ ks)
{
    const int t = blockIdx.x * 256 + threadIdx.x;   // 786432 threads, 8 elems each
    const int half = ELEMS_PER_TENSOR / 8;          // 393216
    const bool is_q = t < half;
    const int idx = (is_q ? t : t - half) * 8;
    const float* src = is_q ? q : k;
    const float sc = is_q ? QSCALE : 1.0f;
    f32x4 a = *(const f32x4*)(src + idx);
    f32x4 b = *(const f32x4*)(src + idx + 4);
    bf16x8 o;
    #pragma unroll
    for (int j = 0; j < 4; ++j) { o[j] = (__bf16)(a[j] * sc); o[4 + j] = (__bf16)(b[j] * sc); }
    *(bf16x8*)((is_q ? qs : ks) + idx) = o;
}

// ---------------- pre-pass: V -> bf16, transposed to [bh][d][s] ----------------
__global__ __launch_bounds__(256)
void cvt_v_kernel(const float* __restrict__ v, __bf16* __restrict__ vt)
{
    const int bh = blockIdx.x >> 5;
    const int s0 = (blockIdx.x & 31) * 64;
    const int tid = threadIdx.x;
    __shared__ __bf16 T[64][LDK];      // T[s][d]
    const int r = tid >> 2, c0 = (tid & 3) * 16;
    const float* vp = v + (size_t)bh * SEQ * DH + (size_t)(s0 + r) * DH + c0;
    __bf16 tmp[16];
    #pragma unroll
    for (int jj = 0; jj < 16; ++jj) tmp[jj] = (__bf16)vp[jj];
    *(bf16x8*)&T[r][c0]     = *(bf16x8*)&tmp[0];
    *(bf16x8*)&T[r][c0 + 8] = *(bf16x8*)&tmp[8];
    __syncthreads();
    const int d = tid >> 2, j0 = (tid & 3) * 16;
    __bf16 o[16];
    #pragma unroll
    for (int jj = 0; jj < 16; ++jj) o[jj] = T[j0 + jj][d];
    __bf16* op = vt + (size_t)bh * DH * SEQ + (size_t)d * SEQ + s0 + j0;
    *(bf16x8*)op       = *(bf16x8*)&o[0];
    *(bf16x8*)(op + 8) = *(bf16x8*)&o[8];
}

// ---------------- main: barrier-free flash attention ----------------
__global__ __launch_bounds__(256, 2)
void fa2_kernel(const __bf16* __restrict__ qs, const __bf16* __restrict__ ks,
                const __bf16* __restrict__ vt, float* __restrict__ out)
{
    const int mt = 31 - (blockIdx.x & 31);   // heavy q-tiles launch first
    const int bh = blockIdx.x >> 5;
    const int tid = threadIdx.x;
    const int w = tid >> 6, lane = tid & 63;
    const int g = lane >> 4, li = lane & 15;
    const int m0 = mt * BM;

    __shared__ __bf16 Ps[4][16][LDK];        // wave-private P tiles

    const __bf16* qh = qs + (size_t)bh * SEQ * DH;
    const __bf16* kh = ks + (size_t)bh * SEQ * DH;
    const __bf16* vh = vt + (size_t)bh * DH * SEQ;   // [d][s]
    float* oh = out + (size_t)bh * SEQ * DH;

    const int qrow = m0 + w * 16 + li;
    bf16x8 qf[2];
    qf[0] = *(const bf16x8*)(qh + (size_t)qrow * DH + g * 8);
    qf[1] = *(const bf16x8*)(qh + (size_t)qrow * DH + 32 + g * 8);

    f32x4 acc[4] = {};
    float mrow[4], lrow[4];
    #pragma unroll
    for (int r = 0; r < 4; ++r) { mrow[r] = -1e30f; lrow[r] = 0.0f; }

    // fragment pointers: K frag (t,c): row kv0+t*16+li, col c*32+g*8
    //                    V frag (t,c): d   t*16+li,    s   kv0+c*32+g*8
    bf16x8 kf[8], vf[8];
    {
        const int kv0 = 0;
        #pragma unroll
        for (int t = 0; t < 4; ++t)
            #pragma unroll
            for (int c = 0; c < 2; ++c) {
                kf[t * 2 + c] = *(const bf16x8*)(kh + (size_t)(kv0 + t * 16 + li) * DH + c * 32 + g * 8);
                vf[t * 2 + c] = *(const bf16x8*)(vh + (size_t)(t * 16 + li) * SEQ + kv0 + c * 32 + g * 8);
            }
    }

    for (int jt = 0; jt <= mt; ++jt) {
        const int kv0 = jt * BN;

        // ---- S = Q K^T (scale pre-folded into Q, base-2 domain) ----
        float s[4][4];
        #pragma unroll
        for (int t = 0; t < 4; ++t) {
            f32x4 sa = {};
            #pragma unroll
            for (int c = 0; c < 2; ++c)
                sa = __builtin_amdgcn_mfma_f32_16x16x32_bf16(qf[c], kf[t * 2 + c], sa, 0, 0, 0);
            #pragma unroll
            for (int r = 0; r < 4; ++r) s[t][r] = sa[r];
        }

        // prefetch next K while softmax runs (kf dead after the MFMAs above)
        if (jt < mt) {
            const int kv1 = kv0 + BN;
            #pragma unroll
            for (int t = 0; t < 4; ++t)
                #pragma unroll
                for (int c = 0; c < 2; ++c)
                    kf[t * 2 + c] = *(const bf16x8*)(kh + (size_t)(kv1 + t * 16 + li) * DH + c * 32 + g * 8);
        }

        // causal mask on the diagonal tile only (wave-uniform branch)
        if (jt == mt) {
            #pragma unroll
            for (int t = 0; t < 4; ++t) {
                const int col = kv0 + t * 16 + li;
                #pragma unroll
                for (int r = 0; r < 4; ++r)
                    if (col > m0 + w * 16 + g * 4 + r) s[t][r] = -1e30f;
            }
        }

        // ---- online softmax (base 2), rows spread over 16 lanes ----
        #pragma unroll
        for (int r = 0; r < 4; ++r) {
            float mx = fmaxf(fmaxf(s[0][r], s[1][r]), fmaxf(s[2][r], s[3][r]));
            #pragma unroll
            for (int off = 1; off < 16; off <<= 1)
                mx = fmaxf(mx, __shfl_xor(mx, off, 64));
            const float mnew = fmaxf(mrow[r], mx);
            const float alpha = EXP2F(mrow[r] - mnew);
            mrow[r] = mnew;
            float ps = 0.0f;
            #pragma unroll
            for (int t = 0; t < 4; ++t) {
                const float p = EXP2F(s[t][r] - mnew);
                s[t][r] = p;
                ps += p;
            }
            #pragma unroll
            for (int off = 1; off < 16; off <<= 1)
                ps += __shfl_xor(ps, off, 64);
            lrow[r] = lrow[r] * alpha + ps;
            #pragma unroll
            for (int t = 0; t < 4; ++t) acc[t][r] *= alpha;
        }

        // ---- P: C-layout -> wave-private LDS -> A-layout (no barrier) ----
        #pragma unroll
        for (int t = 0; t < 4; ++t)
            #pragma unroll
            for (int r = 0; r < 4; ++r)
                Ps[w][g * 4 + r][t * 16 + li] = (__bf16)s[t][r];

        // ---- O += P V ----
        #pragma unroll
        for (int c = 0; c < 2; ++c) {
            bf16x8 pf = *(const bf16x8*)&Ps[w][li][c * 32 + g * 8];
            #pragma unroll
            for (int t = 0; t < 4; ++t)
                acc[t] = __builtin_amdgcn_mfma_f32_16x16x32_bf16(pf, vf[t * 2 + c], acc[t], 0, 0, 0);
        }

        // prefetch next V while next iteration's S/softmax run
        if (jt < mt) {
            const int kv1 = kv0 + BN;
            #pragma unroll
            for (int t = 0; t < 4; ++t)
                #pragma unroll
                for (int c = 0; c < 2; ++c)
                    vf[t * 2 + c] = *(const bf16x8*)(vh + (size_t)(t * 16 + li) * SEQ + kv1 + c * 32 + g * 8);
        }
    }

    #pragma unroll
    for (int r = 0; r < 4; ++r) {
        const int row = m0 + w * 16 + g * 4 + r;
        const float inv = 1.0f / lrow[r];
        float* op = oh + (size_t)row * DH + li;
        #pragma unroll
        for (int t = 0; t < 4; ++t) op[t * 16] = acc[t][r] * inv;
    }
}

// ---------------- fallback (R1 kernel, used only if ws is too small) ----------------
__global__ __launch_bounds__(256, 2)
void fa_causal_kernel(const float* __restrict__ q, const float* __restrict__ k,
                      const float* __restrict__ v, float* __restrict__ out)
{
    const int mt = 31 - (blockIdx.x & 31);
    const int bh = blockIdx.x >> 5;
    const int tid = threadIdx.x;
    const int w = tid >> 6, lane = tid & 63;
    const int g = lane >> 4, li = lane & 15;
    const int m0 = mt * BM;

    __shared__ __bf16 Ks[BN][LDK];
    __shared__ __bf16 Vs[DH][LDK];
    __shared__ __bf16 Ps[4][16][LDK];

    const size_t head_off = (size_t)bh * SEQ * DH;
    const float* qh = q + head_off;
    const float* kh = k + head_off;
    const float* vh = v + head_off;
    float* oh = out + head_off;

    const int qrow = m0 + w * 16 + li;
    bf16x8 qf[2];
    {
        const float* qp = qh + (size_t)qrow * DH + g * 8;
        #pragma unroll
        for (int c = 0; c < 2; ++c) {
            const float* p = qp + c * 32;
            #pragma unroll
            for (int jj = 0; jj < 8; ++jj) qf[c][jj] = (__bf16)p[jj];
        }
    }

    f32x4 acc[4] = {};
    float mrow[4], lrow[4];
    #pragma unroll
    for (int r = 0; r < 4; ++r) { mrow[r] = -1e30f; lrow[r] = 0.0f; }
    const float scale = 0.125f;
    const int srow = tid >> 2, scol = (tid & 3) * 16;

    for (int jt = 0; jt <= mt; ++jt) {
        const int kv0 = jt * BN;
        __syncthreads();
        {
            const float* kp = kh + (size_t)(kv0 + srow) * DH + scol;
            __bf16 tmp[16];
            #pragma unroll
            for (int jj = 0; jj < 16; ++jj) tmp[jj] = (__bf16)kp[jj];
            *(bf16x8*)&Ks[srow][scol]     = *(bf16x8*)&tmp[0];
            *(bf16x8*)&Ks[srow][scol + 8] = *(bf16x8*)&tmp[8];
            const float* vp = vh + (size_t)(kv0 + srow) * DH + scol;
            #pragma unroll
            for (int jj = 0; jj < 16; ++jj) Vs[scol + jj][srow] = (__bf16)vp[jj];
        }
        __syncthreads();

        float s[4][4];
        #pragma unroll
        for (int t = 0; t < 4; ++t) {
            f32x4 sa = {};
            #pragma unroll
            for (int c = 0; c < 2; ++c) {
                bf16x8 kfr = *(const bf16x8*)&Ks[t * 16 + li][c * 32 + g * 8];
                sa = __builtin_amdgcn_mfma_f32_16x16x32_bf16(qf[c], kfr, sa, 0, 0, 0);
            }
            #pragma unroll
            for (int r = 0; r < 4; ++r) s[t][r] = sa[r] * scale;
        }
        if (jt == mt) {
            #pragma unroll
            for (int t = 0; t < 4; ++t) {
                const int col = kv0 + t * 16 + li;
                #pragma unroll
                for (int r = 0; r < 4; ++r)
                    if (col > m0 + w * 16 + g * 4 + r) s[t][r] = -1e30f;
            }
        }
        #pragma unroll
        for (int r = 0; r < 4; ++r) {
            float mx = fmaxf(fmaxf(s[0][r], s[1][r]), fmaxf(s[2][r], s[3][r]));
            #pragma unroll
            for (int off = 1; off < 16; off <<= 1)
                mx = fmaxf(mx, __shfl_xor(mx, off, 64));
            const float mnew = fmaxf(mrow[r], mx);
            const float alpha = __expf(mrow[r] - mnew);
            mrow[r] = mnew;
            float ps = 0.0f;
            #pragma unroll
            for (int t = 0; t < 4; ++t) {
                const float p = __expf(s[t][r] - mnew);
                s[t][r] = p;
                ps += p;
            }
            #pragma unroll
            for (int off = 1; off < 16; off <<= 1)
                ps += __shfl_xor(ps, off, 64);
            lrow[r] = lrow[r] * alpha + ps;
            #pragma unroll
            for (int t = 0; t < 4; ++t) acc[t][r] *= alpha;
        }
        #pragma unroll
        for (int t = 0; t < 4; ++t)
            #pragma unroll
            for (int r = 0; r < 4; ++r)
                Ps[w][g * 4 + r][t * 16 + li] = (__bf16)s[t][r];
        __syncthreads();
        #pragma unroll
        for (int c = 0; c < 2; ++c) {
            bf16x8 pf = *(const bf16x8*)&Ps[w][li][c * 32 + g * 8];
            #pragma unroll
            for (int t = 0; t < 4; ++t) {
                bf16x8 vfr = *(const bf16x8*)&Vs[t * 16 + li][c * 32 + g * 8];
                acc[t] = __builtin_amdgcn_mfma_f32_16x16x32_bf16(pf, vfr, acc[t], 0, 0, 0);
            }
        }
    }
    #pragma unroll
    for (int r = 0; r < 4; ++r) {
        const int row = m0 + w * 16 + g * 4 + r;
        const float inv = 1.0f / lrow[r];
        float* op = oh + (size_t)row * DH + li;
        #pragma unroll
        for (int t = 0; t < 4; ++t) op[t * 16] = acc[t][r] * inv;
    }
}

extern "C" void kernel_launch(void* const* d_in, const int* in_sizes, int n_in,
                              void* d_out, int out_size, void* d_ws, size_t ws_size,
                              hipStream_t stream) {
    (void)in_sizes; (void)n_in; (void)out_size;
    const float* q = (const float*)d_in[0];
    const float* k = (const float*)d_in[1];
    const float* v = (const float*)d_in[2];
    float* out = (float*)d_out;

    if (ws_size >= WS_NEEDED) {
        __bf16* qs = (__bf16*)d_ws;
        __bf16* ks = qs + ELEMS_PER_TENSOR;
        __bf16* vt = ks + ELEMS_PER_TENSOR;
        cvt_qk_kernel<<<dim3(2 * ELEMS_PER_TENSOR / 8 / 256), dim3(256), 0, stream>>>(q, k, qs, ks);
        cvt_v_kernel<<<dim3(NHEADS * 32), dim3(256), 0, stream>>>(v, vt);
        fa2_kernel<<<dim3(NHEADS * 32), dim3(256), 0, stream>>>(qs, ks, vt, out);
    } else {
        fa_causal_kernel<<<dim3(NHEADS * 32), dim3(256), 0, stream>>>(q, k, v, out);
    }
}